// Round 1
// baseline (1797.233 us; speedup 1.0000x reference)
//
#include <hip/hip_runtime.h>
#include <hip/hip_bf16.h>

// CustomLMHead: C[M,N] = X[M,K] @ (Wq[N,K] * scale[N])^T
// M=2048 (2x1024 tokens), N=151936 (vocab), K=896.
// bf16 MFMA 16x16x32, 128x128 tile, BK=32, double-buffered LDS, reg staging
// with on-the-fly dtype conversion (fp32->bf16 for X, int32->bf16 for W).

#define M_DIM 2048
#define N_DIM 151936
#define K_DIM 896
#define BM 128
#define BN 128
#define BK 32
#define NSTEPS (K_DIM / BK)     // 28
#define MB_CNT (M_DIM / BM)     // 16
#define NB_CNT (N_DIM / BN)     // 1187
#define NWG (MB_CNT * NB_CNT)   // 18992 (divisible by 8)

typedef __attribute__((ext_vector_type(8))) short bf16x8;
typedef __attribute__((ext_vector_type(4))) float f32x4;
typedef __attribute__((ext_vector_type(4))) int   i32x4;
typedef __attribute__((ext_vector_type(4))) unsigned int u32x4;

// fp32 -> bf16 round-to-nearest-even (also exact for integer-valued floats <= 2^8)
static __device__ __forceinline__ unsigned short f2bf(float f) {
    unsigned int u = __builtin_bit_cast(unsigned int, f);
    u += 0x7FFFu + ((u >> 16) & 1u);
    return (unsigned short)(u >> 16);
}

__global__ __launch_bounds__(256, 2)
void lmhead_gemm(const float* __restrict__ X,
                 const int* __restrict__ Wq,
                 const float* __restrict__ S,
                 float* __restrict__ O)
{
    __shared__ unsigned short Alds[2][BM][BK];   // 16 KiB
    __shared__ unsigned short Blds[2][BN][BK];   // 16 KiB

    const int tid  = threadIdx.x;
    const int lane = tid & 63;
    const int wave = tid >> 6;
    const int wr   = wave >> 1;   // 0..1 (wave row)
    const int wc   = wave & 1;    // 0..1 (wave col)

    // XCD-chunked bijective swizzle; m varies fastest so the 16 m-blocks that
    // share one 128-row W strip land contiguously on the same XCD's L2.
    const int bid = blockIdx.x;
    const int wg  = (bid & 7) * (NWG / 8) + (bid >> 3);
    const int mb  = wg % MB_CNT;
    const int nb  = wg / MB_CNT;

    // staging map: 2 threads per tile-row, 16 elems (64B) each
    const int srow = tid >> 1;         // 0..127
    const int skh  = (tid & 1) * 16;   // 0 or 16

    const float* aptr = X  + (mb * BM + srow) * K_DIM + skh;
    const int*   wptr = Wq + (nb * BN + srow) * K_DIM + skh;

    f32x4 av[4];
    i32x4 wv[4];

    auto load_tiles = [&](int k0) {
        const f32x4* ap = (const f32x4*)(aptr + k0);
        const i32x4* wp = (const i32x4*)(wptr + k0);
        av[0] = ap[0]; av[1] = ap[1]; av[2] = ap[2]; av[3] = ap[3];
        wv[0] = wp[0]; wv[1] = wp[1]; wv[2] = wp[2]; wv[3] = wp[3];
    };

    auto stage = [&](int buf) {
        unsigned int apk[8], wpk[8];
        #pragma unroll
        for (int i = 0; i < 8; ++i) {
            const unsigned short alo = f2bf(av[(2*i) >> 2][(2*i) & 3]);
            const unsigned short ahi = f2bf(av[(2*i+1) >> 2][(2*i+1) & 3]);
            apk[i] = (unsigned int)alo | ((unsigned int)ahi << 16);
            const unsigned short wlo = f2bf((float)wv[(2*i) >> 2][(2*i) & 3]);
            const unsigned short whi = f2bf((float)wv[(2*i+1) >> 2][(2*i+1) & 3]);
            wpk[i] = (unsigned int)wlo | ((unsigned int)whi << 16);
        }
        *(u32x4*)&Alds[buf][srow][skh]     = u32x4{apk[0], apk[1], apk[2], apk[3]};
        *(u32x4*)&Alds[buf][srow][skh + 8] = u32x4{apk[4], apk[5], apk[6], apk[7]};
        *(u32x4*)&Blds[buf][srow][skh]     = u32x4{wpk[0], wpk[1], wpk[2], wpk[3]};
        *(u32x4*)&Blds[buf][srow][skh + 8] = u32x4{wpk[4], wpk[5], wpk[6], wpk[7]};
    };

    f32x4 acc[4][4];
    #pragma unroll
    for (int i = 0; i < 4; ++i)
        #pragma unroll
        for (int j = 0; j < 4; ++j)
            acc[i][j] = f32x4{0.f, 0.f, 0.f, 0.f};

    load_tiles(0);
    stage(0);
    __syncthreads();

    int cur = 0;
    for (int s = 0; s < NSTEPS; ++s) {
        // T14: issue next-tile global loads first; HBM latency hides under MFMA
        if (s + 1 < NSTEPS) load_tiles((s + 1) * BK);

        // fragment reads (ds_read_b128) + 16 MFMAs on buf[cur]
        bf16x8 af[4], bfr[4];
        const int arow = wr * 64 + (lane & 15);
        const int brow = wc * 64 + (lane & 15);
        const int kb   = (lane >> 4) * 8;
        #pragma unroll
        for (int mf = 0; mf < 4; ++mf)
            af[mf] = *(const bf16x8*)&Alds[cur][arow + mf * 16][kb];
        #pragma unroll
        for (int nf = 0; nf < 4; ++nf)
            bfr[nf] = *(const bf16x8*)&Blds[cur][brow + nf * 16][kb];

        #pragma unroll
        for (int mf = 0; mf < 4; ++mf)
            #pragma unroll
            for (int nf = 0; nf < 4; ++nf)
                acc[mf][nf] = __builtin_amdgcn_mfma_f32_16x16x32_bf16(
                    af[mf], bfr[nf], acc[mf][nf], 0, 0, 0);

        // convert + ds_write next tile into the other buffer
        if (s + 1 < NSTEPS) stage(cur ^ 1);
        __syncthreads();
        cur ^= 1;
    }

    // epilogue: per-column scale in fp32, then store.
    // C/D layout (verified m89/m91): col = lane&15, row = (lane>>4)*4 + reg
    #pragma unroll
    for (int nf = 0; nf < 4; ++nf) {
        const int n = nb * BN + wc * 64 + nf * 16 + (lane & 15);
        const float sc = S[n];
        #pragma unroll
        for (int mf = 0; mf < 4; ++mf) {
            const int m0 = mb * BM + wr * 64 + mf * 16 + ((lane >> 4) << 2);
            #pragma unroll
            for (int r = 0; r < 4; ++r)
                O[(long)(m0 + r) * N_DIM + n] = acc[mf][nf][r] * sc;
        }
    }
}

extern "C" void kernel_launch(void* const* d_in, const int* in_sizes, int n_in,
                              void* d_out, int out_size, void* d_ws, size_t ws_size,
                              hipStream_t stream) {
    const float* X  = (const float*)d_in[0];
    const int*   Wq = (const int*)d_in[1];
    const float* S  = (const float*)d_in[2];
    float*       O  = (float*)d_out;
    lmhead_gemm<<<NWG, 256, 0, stream>>>(X, Wq, S, O);
}

// Round 2
// 1017.163 us; speedup vs baseline: 1.7669x; 1.7669x over previous
//
#include <hip/hip_runtime.h>
#include <hip/hip_bf16.h>

// CustomLMHead: C[M,N] = X[M,K] @ (Wq[N,K] * scale[N])^T
// M=2048, N=151936, K=896.
//
// Fast path (needs 276MB of d_ws): preconvert X(fp32)->bf16 and Wq(int32)->bf16
// into d_ws, then m97-structure GEMM: 128x128 tile, BK=64, single-buffer LDS,
// global_load_lds width-16 staging, bf16 MFMA 16x16x32, fp32 scale epilogue.
// Fallback (small ws): round-1 reg-staging kernel with in-loop conversion.

#define M_DIM 2048
#define N_DIM 151936
#define K_DIM 896

#define BM 128
#define BN 128
#define BK 64
#define NSTEPS (K_DIM / BK)     // 14
#define MB_CNT (M_DIM / BM)     // 16
#define NB_CNT (N_DIM / BN)     // 1187
#define NWG (MB_CNT * NB_CNT)   // 18992 (divisible by 8)

typedef __attribute__((ext_vector_type(8))) short bf16x8;
typedef __attribute__((ext_vector_type(4))) float f32x4;
typedef __attribute__((ext_vector_type(4))) int   i32x4;
typedef __attribute__((ext_vector_type(4))) unsigned int u32x4;

// fp32 -> bf16 round-to-nearest-even (exact for int-valued floats <= 2^8)
static __device__ __forceinline__ unsigned short f2bf(float f) {
    unsigned int u = __builtin_bit_cast(unsigned int, f);
    u += 0x7FFFu + ((u >> 16) & 1u);
    return (unsigned short)(u >> 16);
}

static __device__ __forceinline__ unsigned int pack2(float lo, float hi) {
    return (unsigned int)f2bf(lo) | ((unsigned int)f2bf(hi) << 16);
}

// async global -> LDS, 16 bytes/lane. LDS dest = wave-uniform base + lane*16.
static __device__ __forceinline__ void gload_lds16(const void* g, void* l) {
    __builtin_amdgcn_global_load_lds(
        (const __attribute__((address_space(1))) unsigned int*)g,
        (__attribute__((address_space(3))) unsigned int*)l, 16, 0, 0);
}

// ---------------- preconvert kernels ----------------

__global__ void cvt_x_kernel(const float* __restrict__ X,
                             unsigned short* __restrict__ Xb) {
    const long n8 = (long)M_DIM * K_DIM / 8;
    for (long i = (long)blockIdx.x * blockDim.x + threadIdx.x; i < n8;
         i += (long)gridDim.x * blockDim.x) {
        f32x4 a = ((const f32x4*)X)[2 * i];
        f32x4 b = ((const f32x4*)X)[2 * i + 1];
        u32x4 o;
        o[0] = pack2(a[0], a[1]); o[1] = pack2(a[2], a[3]);
        o[2] = pack2(b[0], b[1]); o[3] = pack2(b[2], b[3]);
        ((u32x4*)Xb)[i] = o;
    }
}

__global__ void cvt_w_kernel(const int* __restrict__ Wq,
                             unsigned short* __restrict__ Wb) {
    const long n8 = (long)N_DIM * K_DIM / 8;
    for (long i = (long)blockIdx.x * blockDim.x + threadIdx.x; i < n8;
         i += (long)gridDim.x * blockDim.x) {
        i32x4 a = ((const i32x4*)Wq)[2 * i];
        i32x4 b = ((const i32x4*)Wq)[2 * i + 1];
        u32x4 o;
        o[0] = pack2((float)a[0], (float)a[1]); o[1] = pack2((float)a[2], (float)a[3]);
        o[2] = pack2((float)b[0], (float)b[1]); o[3] = pack2((float)b[2], (float)b[3]);
        ((u32x4*)Wb)[i] = o;
    }
}

// ---------------- main GEMM (fast path, m97 structure) ----------------

__global__ __launch_bounds__(256, 2)
void lmhead_gemm_bf16(const unsigned short* __restrict__ Xb,
                      const unsigned short* __restrict__ Wb,
                      const float* __restrict__ S,
                      float* __restrict__ O)
{
    __shared__ unsigned short Alds[BM][BK];   // 16 KiB
    __shared__ unsigned short Blds[BN][BK];   // 16 KiB

    const int tid  = threadIdx.x;
    const int lane = tid & 63;
    const int wave = tid >> 6;
    const int wr   = wave >> 1;   // 0..1
    const int wc   = wave & 1;    // 0..1

    // XCD-chunked bijective swizzle (NWG % 8 == 0); m varies fastest so the
    // 16 m-blocks sharing one 128-row W strip co-locate on one XCD's L2.
    const int bid = blockIdx.x;
    const int wg  = (bid & 7) * (NWG / 8) + (bid >> 3);
    const int mb  = wg % MB_CNT;
    const int nb  = wg / MB_CNT;

    // staging map: tile = 128 rows x 64 elems (128B/row) = 16 chunks of 1024B.
    // wave w handles chunks 4w..4w+3 per matrix. Within a chunk, lane l's 16B
    // lands at lds byte l*16 -> row_in_chunk = l>>3, elem = (l&7)*8.
    const int c0    = wave * 4;
    const int lrow  = lane >> 3;        // 0..7
    const int lelem = (lane & 7) * 8;   // 0..56

    const unsigned short* abase = Xb + (size_t)(mb * BM) * K_DIM;
    const unsigned short* bbase = Wb + (size_t)(nb * BN) * K_DIM;

    auto stage = [&](int k0) {
        #pragma unroll
        for (int i = 0; i < 4; ++i) {
            const int row = (c0 + i) * 8 + lrow;
            gload_lds16(abase + (size_t)row * K_DIM + k0 + lelem,
                        &Alds[(c0 + i) * 8][0]);
            gload_lds16(bbase + (size_t)row * K_DIM + k0 + lelem,
                        &Blds[(c0 + i) * 8][0]);
        }
    };

    f32x4 acc[4][4];
    #pragma unroll
    for (int i = 0; i < 4; ++i)
        #pragma unroll
        for (int j = 0; j < 4; ++j)
            acc[i][j] = f32x4{0.f, 0.f, 0.f, 0.f};

    stage(0);

    const int arow = wr * 64 + (lane & 15);
    const int brow = wc * 64 + (lane & 15);
    const int kb   = (lane >> 4) * 8;

    for (int s = 0; s < NSTEPS; ++s) {
        __syncthreads();   // drains vmcnt(0): staged tile is in LDS

        #pragma unroll
        for (int kk = 0; kk < 2; ++kk) {
            bf16x8 af[4], bfr[4];
            #pragma unroll
            for (int mf = 0; mf < 4; ++mf)
                af[mf] = *(const bf16x8*)&Alds[arow + mf * 16][kk * 32 + kb];
            #pragma unroll
            for (int nf = 0; nf < 4; ++nf)
                bfr[nf] = *(const bf16x8*)&Blds[brow + nf * 16][kk * 32 + kb];
            #pragma unroll
            for (int mf = 0; mf < 4; ++mf)
                #pragma unroll
                for (int nf = 0; nf < 4; ++nf)
                    acc[mf][nf] = __builtin_amdgcn_mfma_f32_16x16x32_bf16(
                        af[mf], bfr[nf], acc[mf][nf], 0, 0, 0);
        }

        __syncthreads();   // all reads done before restaging
        if (s + 1 < NSTEPS) stage((s + 1) * BK);
    }

    // epilogue: per-column scale in fp32. C/D map: col=lane&15, row=(lane>>4)*4+r
    #pragma unroll
    for (int nf = 0; nf < 4; ++nf) {
        const int n = nb * BN + wc * 64 + nf * 16 + (lane & 15);
        const float sc = S[n];
        #pragma unroll
        for (int mf = 0; mf < 4; ++mf) {
            const int m0 = mb * BM + wr * 64 + mf * 16 + ((lane >> 4) << 2);
            #pragma unroll
            for (int r = 0; r < 4; ++r)
                O[(long)(m0 + r) * N_DIM + n] = acc[mf][nf][r] * sc;
        }
    }
}

// ---------------- fallback (round-1): reg staging + in-loop convert ----------------

#define FBK 32
#define FNSTEPS (K_DIM / FBK)

__global__ __launch_bounds__(256, 2)
void lmhead_gemm_conv(const float* __restrict__ X,
                      const int* __restrict__ Wq,
                      const float* __restrict__ S,
                      float* __restrict__ O)
{
    __shared__ unsigned short Alds[2][BM][FBK];
    __shared__ unsigned short Blds[2][BN][FBK];

    const int tid  = threadIdx.x;
    const int lane = tid & 63;
    const int wave = tid >> 6;
    const int wr   = wave >> 1;
    const int wc   = wave & 1;

    const int bid = blockIdx.x;
    const int wg  = (bid & 7) * (NWG / 8) + (bid >> 3);
    const int mb  = wg % MB_CNT;
    const int nb  = wg / MB_CNT;

    const int srow = tid >> 1;
    const int skh  = (tid & 1) * 16;

    const float* aptr = X  + (size_t)(mb * BM + srow) * K_DIM + skh;
    const int*   wptr = Wq + (size_t)(nb * BN + srow) * K_DIM + skh;

    f32x4 av[4];
    i32x4 wv[4];

    auto load_tiles = [&](int k0) {
        const f32x4* ap = (const f32x4*)(aptr + k0);
        const i32x4* wp = (const i32x4*)(wptr + k0);
        av[0] = ap[0]; av[1] = ap[1]; av[2] = ap[2]; av[3] = ap[3];
        wv[0] = wp[0]; wv[1] = wp[1]; wv[2] = wp[2]; wv[3] = wp[3];
    };

    auto stage = [&](int buf) {
        unsigned int apk[8], wpk[8];
        #pragma unroll
        for (int i = 0; i < 8; ++i) {
            apk[i] = pack2(av[(2*i) >> 2][(2*i) & 3], av[(2*i+1) >> 2][(2*i+1) & 3]);
            wpk[i] = pack2((float)wv[(2*i) >> 2][(2*i) & 3], (float)wv[(2*i+1) >> 2][(2*i+1) & 3]);
        }
        *(u32x4*)&Alds[buf][srow][skh]     = u32x4{apk[0], apk[1], apk[2], apk[3]};
        *(u32x4*)&Alds[buf][srow][skh + 8] = u32x4{apk[4], apk[5], apk[6], apk[7]};
        *(u32x4*)&Blds[buf][srow][skh]     = u32x4{wpk[0], wpk[1], wpk[2], wpk[3]};
        *(u32x4*)&Blds[buf][srow][skh + 8] = u32x4{wpk[4], wpk[5], wpk[6], wpk[7]};
    };

    f32x4 acc[4][4];
    #pragma unroll
    for (int i = 0; i < 4; ++i)
        #pragma unroll
        for (int j = 0; j < 4; ++j)
            acc[i][j] = f32x4{0.f, 0.f, 0.f, 0.f};

    load_tiles(0);
    stage(0);
    __syncthreads();

    int cur = 0;
    for (int s = 0; s < FNSTEPS; ++s) {
        if (s + 1 < FNSTEPS) load_tiles((s + 1) * FBK);

        bf16x8 af[4], bfr[4];
        const int arow = wr * 64 + (lane & 15);
        const int brow = wc * 64 + (lane & 15);
        const int kb   = (lane >> 4) * 8;
        #pragma unroll
        for (int mf = 0; mf < 4; ++mf)
            af[mf] = *(const bf16x8*)&Alds[cur][arow + mf * 16][kb];
        #pragma unroll
        for (int nf = 0; nf < 4; ++nf)
            bfr[nf] = *(const bf16x8*)&Blds[cur][brow + nf * 16][kb];

        #pragma unroll
        for (int mf = 0; mf < 4; ++mf)
            #pragma unroll
            for (int nf = 0; nf < 4; ++nf)
                acc[mf][nf] = __builtin_amdgcn_mfma_f32_16x16x32_bf16(
                    af[mf], bfr[nf], acc[mf][nf], 0, 0, 0);

        if (s + 1 < FNSTEPS) stage(cur ^ 1);
        __syncthreads();
        cur ^= 1;
    }

    #pragma unroll
    for (int nf = 0; nf < 4; ++nf) {
        const int n = nb * BN + wc * 64 + nf * 16 + (lane & 15);
        const float sc = S[n];
        #pragma unroll
        for (int mf = 0; mf < 4; ++mf) {
            const int m0 = mb * BM + wr * 64 + mf * 16 + ((lane >> 4) << 2);
            #pragma unroll
            for (int r = 0; r < 4; ++r)
                O[(long)(m0 + r) * N_DIM + n] = acc[mf][nf][r] * sc;
        }
    }
}

// ---------------- launch ----------------

extern "C" void kernel_launch(void* const* d_in, const int* in_sizes, int n_in,
                              void* d_out, int out_size, void* d_ws, size_t ws_size,
                              hipStream_t stream) {
    const float* X  = (const float*)d_in[0];
    const int*   Wq = (const int*)d_in[1];
    const float* S  = (const float*)d_in[2];
    float*       O  = (float*)d_out;

    const size_t XB_BYTES = (size_t)M_DIM * K_DIM * 2;   // 3,670,016
    const size_t WB_BYTES = (size_t)N_DIM * K_DIM * 2;   // 272,269,312

    if (ws_size >= XB_BYTES + WB_BYTES) {
        unsigned short* Xb = (unsigned short*)d_ws;
        unsigned short* Wb = (unsigned short*)((char*)d_ws + XB_BYTES);
        cvt_x_kernel<<<896, 256, 0, stream>>>(X, Xb);
        cvt_w_kernel<<<2048, 256, 0, stream>>>(Wq, Wb);
        lmhead_gemm_bf16<<<NWG, 256, 0, stream>>>(Xb, Wb, S, O);
    } else {
        lmhead_gemm_conv<<<NWG, 256, 0, stream>>>(X, Wq, S, O);
    }
}

// Round 3
// 990.358 us; speedup vs baseline: 1.8147x; 1.0271x over previous
//
#include <hip/hip_runtime.h>
#include <hip/hip_bf16.h>

// CustomLMHead: C[M,N] = X[M,K] @ (Wq[N,K] * scale[N])^T
// M=2048, N=151936, K=896.
//
// Fast path: preconvert X(fp32)->bf16, Wq(int32)->bf16 into d_ws, then an
// 8-phase 256x256 GEMM (T2 LDS swizzle + T3/T4 counted-vmcnt pipeline + T5
// setprio), bf16 MFMA 16x16x32, fp32 per-column scale epilogue.
// Fallback (small ws): reg-staging kernel with in-loop conversion.

#define M_DIM 2048
#define N_DIM 151936
#define K_DIM 896

// ---- 8-phase GEMM geometry ----
#define BM 256
#define BN 256
#define BK 64
#define NKT (K_DIM / BK)                 // 14
#define MB_CNT (M_DIM / BM)              // 8
#define NB_CNT ((N_DIM + BN - 1) / BN)   // 594 (tail block cols 151808..152063)
#define NWG (MB_CNT * NB_CNT)            // 4752, divisible by 8

typedef __attribute__((ext_vector_type(8))) short bf16x8;
typedef __attribute__((ext_vector_type(4))) float f32x4;
typedef __attribute__((ext_vector_type(4))) int   i32x4;
typedef __attribute__((ext_vector_type(4))) unsigned int u32x4;

// fp32 -> bf16 round-to-nearest-even (exact for int-valued floats <= 2^8)
static __device__ __forceinline__ unsigned short f2bf(float f) {
    unsigned int u = __builtin_bit_cast(unsigned int, f);
    u += 0x7FFFu + ((u >> 16) & 1u);
    return (unsigned short)(u >> 16);
}
static __device__ __forceinline__ unsigned int pack2(float lo, float hi) {
    return (unsigned int)f2bf(lo) | ((unsigned int)f2bf(hi) << 16);
}
// async global -> LDS, 16 B/lane; LDS dest = wave-uniform base + lane*16
static __device__ __forceinline__ void gload_lds16(const void* g, void* l) {
    __builtin_amdgcn_global_load_lds(
        (const __attribute__((address_space(1))) unsigned int*)g,
        (__attribute__((address_space(3))) unsigned int*)l, 16, 0, 0);
}

// ---------------- preconvert kernels ----------------

__global__ void cvt_x_kernel(const float* __restrict__ X,
                             unsigned short* __restrict__ Xb) {
    const long n8 = (long)M_DIM * K_DIM / 8;
    for (long i = (long)blockIdx.x * blockDim.x + threadIdx.x; i < n8;
         i += (long)gridDim.x * blockDim.x) {
        f32x4 a = ((const f32x4*)X)[2 * i];
        f32x4 b = ((const f32x4*)X)[2 * i + 1];
        u32x4 o;
        o[0] = pack2(a[0], a[1]); o[1] = pack2(a[2], a[3]);
        o[2] = pack2(b[0], b[1]); o[3] = pack2(b[2], b[3]);
        ((u32x4*)Xb)[i] = o;
    }
}

__global__ void cvt_w_kernel(const int* __restrict__ Wq,
                             unsigned short* __restrict__ Wb) {
    const long n8 = (long)N_DIM * K_DIM / 8;
    for (long i = (long)blockIdx.x * blockDim.x + threadIdx.x; i < n8;
         i += (long)gridDim.x * blockDim.x) {
        i32x4 a = ((const i32x4*)Wq)[2 * i];
        i32x4 b = ((const i32x4*)Wq)[2 * i + 1];
        u32x4 o;
        o[0] = pack2((float)a[0], (float)a[1]); o[1] = pack2((float)a[2], (float)a[3]);
        o[2] = pack2((float)b[0], (float)b[1]); o[3] = pack2((float)b[2], (float)b[3]);
        ((u32x4*)Wb)[i] = o;
    }
}

// ---------------- 8-phase 256x256 GEMM ----------------
//
// Phases per K-tile (4): (kh0,q0)(kh0,q1)(kh1,q0)(kh1,q1); q = row-half of the
// wave's 128-row output. Staging (2 gload_lds per phase):
//   P0: A-kh1 of tile t+1   P1: B-kh1 of tile t+1   (into buf^1)
//   P2: A-kh0 of tile t+2   P3: B-kh0 of tile t+2   (into buf, kh0 freed at P1)
// Counted waits: vmcnt(8) at P0/P2 (data needed is always >= 8 loads old).

__global__ __launch_bounds__(512, 2)
void lmhead_gemm_8ph(const unsigned short* __restrict__ Xb,
                     const unsigned short* __restrict__ Wb,
                     const float* __restrict__ S,
                     float* __restrict__ O)
{
    // [buf][mat A=0/B=1][khalf][row][col 32 bf16] = 128 KiB
    __shared__ unsigned short lds[2][2][2][256][32];

    const int tid  = threadIdx.x;
    const int lane = tid & 63;
    const int wave = tid >> 6;      // 0..7, wave-uniform
    const int wr   = wave >> 2;     // 0..1
    const int wc   = wave & 3;      // 0..3

    // XCD-chunked bijective swizzle; m fastest so 8 m-blocks sharing one
    // 256-row W strip co-locate on one XCD's L2.
    const int bid = blockIdx.x;
    const int wg  = (bid & 7) * (NWG / 8) + (bid >> 3);
    const int mb  = wg % MB_CNT;
    const int nb  = wg / MB_CNT;

    // ---- staging per-lane constants ----
    // one stage call = 8 waves x 64 lanes x 16B = 128 rows of 64B (one K-half
    // of a 128-row half). dest row = 128j + wave*16 + (lane>>2), phys slot =
    // lane&3. T2 swizzle: phys = logical ^ ((row>>1)&3)  =>  source logical
    // slot = (lane&3) ^ ((lane>>3)&3)  (per-lane constant).
    const int lrow  = lane >> 2;
    const int lslot = (lane & 3) ^ ((lane >> 3) & 3);
    const unsigned short* srcA[2];
    const unsigned short* srcB[2];
    {
        const int r0 = wave * 16 + lrow;
        srcA[0] = Xb + (size_t)(mb * BM + r0      ) * K_DIM + lslot * 8;
        srcA[1] = Xb + (size_t)(mb * BM + 128 + r0) * K_DIM + lslot * 8;
        int b0 = nb * BN + r0;        if (b0 > N_DIM - 1) b0 = N_DIM - 1;
        int b1 = nb * BN + 128 + r0;  if (b1 > N_DIM - 1) b1 = N_DIM - 1;
        srcB[0] = Wb + (size_t)b0 * K_DIM + lslot * 8;
        srcB[1] = Wb + (size_t)b1 * K_DIM + lslot * 8;
    }

    auto stage = [&](int b2, int mat, int kh, int k0) {
        const unsigned short* s0 = (mat ? srcB[0] : srcA[0]) + k0;
        const unsigned short* s1 = (mat ? srcB[1] : srcA[1]) + k0;
        gload_lds16(s0, &lds[b2][mat][kh][wave * 16][0]);
        gload_lds16(s1, &lds[b2][mat][kh][128 + wave * 16][0]);
    };

    // ---- fragment-read per-lane constants ----
    // frag row = R0(mult of 16) + (lane&15); logical k-octet = lane>>4;
    // phys = logical ^ ((row>>1)&3) = (lane>>4) ^ ((lane>>1)&3): 2-way banks.
    const int physoff   = ((lane >> 4) ^ ((lane >> 1) & 3)) * 8;
    const int arow_base = wr * 128 + (lane & 15);
    const int brow_base = wc * 64  + (lane & 15);

    f32x4 acc[8][4];
    #pragma unroll
    for (int i = 0; i < 8; ++i)
        #pragma unroll
        for (int j = 0; j < 4; ++j)
            acc[i][j] = f32x4{0.f, 0.f, 0.f, 0.f};

    // prologue: tile0-kh0 (loads 1-4), tile0-kh1 (5-8), tile1-kh0 (9-12)
    stage(0, 0, 0, 0);   stage(0, 1, 0, 0);
    stage(0, 0, 1, 32);  stage(0, 1, 1, 32);
    stage(1, 0, 0, 64);  stage(1, 1, 0, 64);

    bf16x8 af[4], bf[4];

#define READ_A(B, KH, Q) do { \
    _Pragma("unroll") \
    for (int mf = 0; mf < 4; ++mf) \
        af[mf] = *(const bf16x8*)&lds[B][0][KH][arow_base + (Q)*64 + mf*16][physoff]; \
} while (0)
#define READ_B(B, KH) do { \
    _Pragma("unroll") \
    for (int nf = 0; nf < 4; ++nf) \
        bf[nf] = *(const bf16x8*)&lds[B][1][KH][brow_base + nf*16][physoff]; \
} while (0)
#define MFMA_Q(Q) do { \
    __builtin_amdgcn_s_setprio(1); \
    _Pragma("unroll") \
    for (int mf = 0; mf < 4; ++mf) { \
        _Pragma("unroll") \
        for (int nf = 0; nf < 4; ++nf) \
            acc[(Q)*4 + mf][nf] = __builtin_amdgcn_mfma_f32_16x16x32_bf16( \
                af[mf], bf[nf], acc[(Q)*4 + mf][nf], 0, 0, 0); \
    } \
    __builtin_amdgcn_s_setprio(0); \
} while (0)

    for (int t = 0; t < NKT - 1; ++t) {
        const int b   = t & 1;
        const int kN1 = (t + 1) * BK + 32;   // kh1 of tile t+1
        const int kN0 = (t + 2) * BK;        // kh0 of tile t+2

        // P0: kh0,q0 — needs tile t kh0 (staged t-2 P2/P3; 8 newer loads exist)
        asm volatile("s_waitcnt vmcnt(8)" ::: "memory");
        __builtin_amdgcn_s_barrier();
        READ_A(b, 0, 0); READ_B(b, 0);
        stage(b ^ 1, 0, 1, kN1);
        MFMA_Q(0);

        // P1: kh0,q1
        __builtin_amdgcn_s_barrier();
        READ_A(b, 0, 1);
        stage(b ^ 1, 1, 1, kN1);
        MFMA_Q(1);

        // P2: kh1,q0 — needs tile t kh1 (staged t-1 P0/P1; 8 newer loads exist)
        asm volatile("s_waitcnt vmcnt(8)" ::: "memory");
        __builtin_amdgcn_s_barrier();
        READ_A(b, 1, 0); READ_B(b, 1);
        if (t < NKT - 2) stage(b, 0, 0, kN0);   // kh0 of buf b freed at P1
        MFMA_Q(0);

        // P3: kh1,q1
        __builtin_amdgcn_s_barrier();
        READ_A(b, 1, 1);
        if (t < NKT - 2) stage(b, 1, 0, kN0);
        MFMA_Q(1);
    }

    // peeled last tile (t = NKT-1, buf 1): drain 4 -> 0
    {
        const int b = (NKT - 1) & 1;
        asm volatile("s_waitcnt vmcnt(4)" ::: "memory");
        __builtin_amdgcn_s_barrier();
        READ_A(b, 0, 0); READ_B(b, 0);
        MFMA_Q(0);
        __builtin_amdgcn_s_barrier();
        READ_A(b, 0, 1);
        MFMA_Q(1);
        asm volatile("s_waitcnt vmcnt(0)" ::: "memory");
        __builtin_amdgcn_s_barrier();
        READ_A(b, 1, 0); READ_B(b, 1);
        MFMA_Q(0);
        __builtin_amdgcn_s_barrier();
        READ_A(b, 1, 1);
        MFMA_Q(1);
    }

#undef READ_A
#undef READ_B
#undef MFMA_Q

    // epilogue: per-column scale in fp32. C/D map: col=lane&15, row=(lane>>4)*4+r
    #pragma unroll
    for (int nf = 0; nf < 4; ++nf) {
        const int n = nb * BN + wc * 64 + nf * 16 + (lane & 15);
        if (n < N_DIM) {
            const float sc = S[n];
            #pragma unroll
            for (int a = 0; a < 8; ++a) {
                const int m0 = mb * BM + wr * 128 + a * 16 + ((lane >> 4) << 2);
                #pragma unroll
                for (int r = 0; r < 4; ++r)
                    O[(size_t)(m0 + r) * N_DIM + n] = acc[a][nf][r] * sc;
            }
        }
    }
}

// ---------------- fallback: reg staging + in-loop convert ----------------

#define FBM 128
#define FBN 128
#define FBK 32
#define FNSTEPS (K_DIM / FBK)
#define FMB (M_DIM / FBM)        // 16
#define FNB (N_DIM / FBN)        // 1187
#define FNWG (FMB * FNB)

__global__ __launch_bounds__(256, 2)
void lmhead_gemm_conv(const float* __restrict__ X,
                      const int* __restrict__ Wq,
                      const float* __restrict__ S,
                      float* __restrict__ O)
{
    __shared__ unsigned short Alds[2][FBM][FBK];
    __shared__ unsigned short Blds[2][FBN][FBK];

    const int tid  = threadIdx.x;
    const int lane = tid & 63;
    const int wave = tid >> 6;
    const int wr   = wave >> 1;
    const int wc   = wave & 1;

    const int bid = blockIdx.x;
    const int wg  = (bid & 7) * (FNWG / 8) + (bid >> 3);
    const int mb  = wg % FMB;
    const int nb  = wg / FMB;

    const int srow = tid >> 1;
    const int skh  = (tid & 1) * 16;

    const float* aptr = X  + (size_t)(mb * FBM + srow) * K_DIM + skh;
    const int*   wptr = Wq + (size_t)(nb * FBN + srow) * K_DIM + skh;

    f32x4 av[4];
    i32x4 wv[4];

    auto load_tiles = [&](int k0) {
        const f32x4* ap = (const f32x4*)(aptr + k0);
        const i32x4* wp = (const i32x4*)(wptr + k0);
        av[0] = ap[0]; av[1] = ap[1]; av[2] = ap[2]; av[3] = ap[3];
        wv[0] = wp[0]; wv[1] = wp[1]; wv[2] = wp[2]; wv[3] = wp[3];
    };

    auto stage = [&](int buf) {
        unsigned int apk[8], wpk[8];
        #pragma unroll
        for (int i = 0; i < 8; ++i) {
            apk[i] = pack2(av[(2*i) >> 2][(2*i) & 3], av[(2*i+1) >> 2][(2*i+1) & 3]);
            wpk[i] = pack2((float)wv[(2*i) >> 2][(2*i) & 3], (float)wv[(2*i+1) >> 2][(2*i+1) & 3]);
        }
        *(u32x4*)&Alds[buf][srow][skh]     = u32x4{apk[0], apk[1], apk[2], apk[3]};
        *(u32x4*)&Alds[buf][srow][skh + 8] = u32x4{apk[4], apk[5], apk[6], apk[7]};
        *(u32x4*)&Blds[buf][srow][skh]     = u32x4{wpk[0], wpk[1], wpk[2], wpk[3]};
        *(u32x4*)&Blds[buf][srow][skh + 8] = u32x4{wpk[4], wpk[5], wpk[6], wpk[7]};
    };

    f32x4 acc[4][4];
    #pragma unroll
    for (int i = 0; i < 4; ++i)
        #pragma unroll
        for (int j = 0; j < 4; ++j)
            acc[i][j] = f32x4{0.f, 0.f, 0.f, 0.f};

    load_tiles(0);
    stage(0);
    __syncthreads();

    int cur = 0;
    for (int s = 0; s < FNSTEPS; ++s) {
        if (s + 1 < FNSTEPS) load_tiles((s + 1) * FBK);

        bf16x8 af[4], bfr[4];
        const int arow = wr * 64 + (lane & 15);
        const int brow = wc * 64 + (lane & 15);
        const int kb   = (lane >> 4) * 8;
        #pragma unroll
        for (int mf = 0; mf < 4; ++mf)
            af[mf] = *(const bf16x8*)&Alds[cur][arow + mf * 16][kb];
        #pragma unroll
        for (int nf = 0; nf < 4; ++nf)
            bfr[nf] = *(const bf16x8*)&Blds[cur][brow + nf * 16][kb];

        #pragma unroll
        for (int mf = 0; mf < 4; ++mf)
            #pragma unroll
            for (int nf = 0; nf < 4; ++nf)
                acc[mf][nf] = __builtin_amdgcn_mfma_f32_16x16x32_bf16(
                    af[mf], bfr[nf], acc[mf][nf], 0, 0, 0);

        if (s + 1 < FNSTEPS) stage(cur ^ 1);
        __syncthreads();
        cur ^= 1;
    }

    #pragma unroll
    for (int nf = 0; nf < 4; ++nf) {
        const int n = nb * FBN + wc * 64 + nf * 16 + (lane & 15);
        const float sc = S[n];
        #pragma unroll
        for (int mf = 0; mf < 4; ++mf) {
            const int m0 = mb * FBM + wr * 64 + mf * 16 + ((lane >> 4) << 2);
            #pragma unroll
            for (int r = 0; r < 4; ++r)
                O[(size_t)(m0 + r) * N_DIM + n] = acc[mf][nf][r] * sc;
        }
    }
}

// ---------------- launch ----------------

extern "C" void kernel_launch(void* const* d_in, const int* in_sizes, int n_in,
                              void* d_out, int out_size, void* d_ws, size_t ws_size,
                              hipStream_t stream) {
    const float* X  = (const float*)d_in[0];
    const int*   Wq = (const int*)d_in[1];
    const float* S  = (const float*)d_in[2];
    float*       O  = (float*)d_out;

    const size_t XB_BYTES = (size_t)M_DIM * K_DIM * 2;   // 3,670,016
    const size_t WB_BYTES = (size_t)N_DIM * K_DIM * 2;   // 272,269,312

    if (ws_size >= XB_BYTES + WB_BYTES) {
        unsigned short* Xb = (unsigned short*)d_ws;
        unsigned short* Wb = (unsigned short*)((char*)d_ws + XB_BYTES);
        cvt_x_kernel<<<896, 256, 0, stream>>>(X, Xb);
        cvt_w_kernel<<<2048, 256, 0, stream>>>(Wq, Wb);
        lmhead_gemm_8ph<<<NWG, 512, 0, stream>>>(Xb, Wb, S, O);
    } else {
        lmhead_gemm_conv<<<FNWG, 256, 0, stream>>>(X, Wq, S, O);
    }
}

// Round 5
// 875.802 us; speedup vs baseline: 2.0521x; 1.1308x over previous
//
#include <hip/hip_runtime.h>
#include <hip/hip_bf16.h>

// CustomLMHead: C[M,N] = X[M,K] @ (Wq[N,K] * scale[N])^T
// M=2048, N=151936, K=896.
//
// Fast path: preconvert X(fp32)->bf16, Wq(int32)->bf16 into d_ws, then an
// 8-phase 256x256 GEMM (T2 swizzle, T3/T4 counted vmcnt, T5 setprio) with
// reads-before-barrier overlap. CROSS-WAVE SYNC RULE: every counted vmcnt
// sits BEFORE a barrier, and the ds_reads of the covered data come AFTER
// that barrier (vmcnt->barrier->read = valid happens-before; vmcnt alone is
// wave-local). LDS-coalesced f32x4 epilogue.
// Fallback (small ws): reg-staging kernel with in-loop conversion.

#define M_DIM 2048
#define N_DIM 151936
#define K_DIM 896

#define BM 256
#define BN 256
#define BK 64
#define NKT (K_DIM / BK)                 // 14
#define MB_CNT (M_DIM / BM)              // 8
#define NB_CNT ((N_DIM + BN - 1) / BN)   // 594 (tail block cols 151808..152063)
#define NWG (MB_CNT * NB_CNT)            // 4752, divisible by 8

typedef __attribute__((ext_vector_type(8))) short bf16x8;
typedef __attribute__((ext_vector_type(4))) float f32x4;
typedef __attribute__((ext_vector_type(4))) int   i32x4;
typedef __attribute__((ext_vector_type(4))) unsigned int u32x4;

static __device__ __forceinline__ unsigned short f2bf(float f) {
    unsigned int u = __builtin_bit_cast(unsigned int, f);
    u += 0x7FFFu + ((u >> 16) & 1u);
    return (unsigned short)(u >> 16);
}
static __device__ __forceinline__ unsigned int pack2(float lo, float hi) {
    return (unsigned int)f2bf(lo) | ((unsigned int)f2bf(hi) << 16);
}
static __device__ __forceinline__ void gload_lds16(const void* g, void* l) {
    __builtin_amdgcn_global_load_lds(
        (const __attribute__((address_space(1))) unsigned int*)g,
        (__attribute__((address_space(3))) unsigned int*)l, 16, 0, 0);
}

// ---------------- preconvert kernels ----------------

__global__ void cvt_x_kernel(const float* __restrict__ X,
                             unsigned short* __restrict__ Xb) {
    const long n8 = (long)M_DIM * K_DIM / 8;
    for (long i = (long)blockIdx.x * blockDim.x + threadIdx.x; i < n8;
         i += (long)gridDim.x * blockDim.x) {
        f32x4 a = ((const f32x4*)X)[2 * i];
        f32x4 b = ((const f32x4*)X)[2 * i + 1];
        u32x4 o;
        o[0] = pack2(a[0], a[1]); o[1] = pack2(a[2], a[3]);
        o[2] = pack2(b[0], b[1]); o[3] = pack2(b[2], b[3]);
        ((u32x4*)Xb)[i] = o;
    }
}

__global__ void cvt_w_kernel(const int* __restrict__ Wq,
                             unsigned short* __restrict__ Wb) {
    const long n8 = (long)N_DIM * K_DIM / 8;
    for (long i = (long)blockIdx.x * blockDim.x + threadIdx.x; i < n8;
         i += (long)gridDim.x * blockDim.x) {
        i32x4 a = ((const i32x4*)Wq)[2 * i];
        i32x4 b = ((const i32x4*)Wq)[2 * i + 1];
        u32x4 o;
        o[0] = pack2((float)a[0], (float)a[1]); o[1] = pack2((float)a[2], (float)a[3]);
        o[2] = pack2((float)b[0], (float)b[1]); o[3] = pack2((float)b[2], (float)b[3]);
        ((u32x4*)Wb)[i] = o;
    }
}

// ---------------- 8-phase 256x256 GEMM ----------------
// Per tile t (buf b): P0/P1 consume (b,kh0) q0/q1; P2/P3 consume (b,kh1).
// Staging: P0: A(t+1,kh1)  P1: B(t+1,kh1)  P2: A(t+2,kh0)  P3: B(t+2,kh0).
// vmcnt(8) before P1's and P3's barrier-A:
//   at t.P1: newest 8 loads = {tP1,tP0,(t-1)P3,(t-1)P2} stages
//            -> (t-1)P0/P1 (= tile t kh1) retired; P2/P3 reads safe.
//   at t.P3: newest 8 = {tP3,tP2,tP1,tP0} -> (t-1)P2/P3 (= tile t+1 kh0)
//            retired; (t+1).P0 reads safe.

#define SCHED0 __builtin_amdgcn_sched_barrier(0)
#define VMCNT(N) asm volatile("s_waitcnt vmcnt(" #N ")" ::: "memory")

__global__ __launch_bounds__(512, 2)
void lmhead_gemm_8ph(const unsigned short* __restrict__ Xb,
                     const unsigned short* __restrict__ Wb,
                     const float* __restrict__ S,
                     float* __restrict__ O)
{
    // [buf][mat A=0/B=1][khalf][row][col 32 bf16] = 128 KiB
    __shared__ unsigned short lds[2][2][2][256][32];

    const int tid  = threadIdx.x;
    const int lane = tid & 63;
    const int wave = tid >> 6;      // 0..7
    const int wr   = wave >> 2;     // 0..1
    const int wc   = wave & 3;      // 0..3

    const int bid = blockIdx.x;
    const int wg  = (bid & 7) * (NWG / 8) + (bid >> 3);
    const int mb  = wg % MB_CNT;
    const int nb  = wg / MB_CNT;

    // staging: dest row = 128j + wave*16 + (lane>>2), phys 16B-slot = lane&3.
    // T2 swizzle phys = logical ^ ((row>>1)&3) -> source slot = (l&3)^((l>>3)&3).
    const int lrow  = lane >> 2;
    const int lslot = (lane & 3) ^ ((lane >> 3) & 3);
    const unsigned short* srcA[2];
    const unsigned short* srcB[2];
    {
        const int r0 = wave * 16 + lrow;
        srcA[0] = Xb + (size_t)(mb * BM + r0      ) * K_DIM + lslot * 8;
        srcA[1] = Xb + (size_t)(mb * BM + 128 + r0) * K_DIM + lslot * 8;
        int b0 = nb * BN + r0;        if (b0 > N_DIM - 1) b0 = N_DIM - 1;
        int b1 = nb * BN + 128 + r0;  if (b1 > N_DIM - 1) b1 = N_DIM - 1;
        srcB[0] = Wb + (size_t)b0 * K_DIM + lslot * 8;
        srcB[1] = Wb + (size_t)b1 * K_DIM + lslot * 8;
    }

    auto stage = [&](int b2, int mat, int kh, int k0) {
        const unsigned short* s0 = (mat ? srcB[0] : srcA[0]) + k0;
        const unsigned short* s1 = (mat ? srcB[1] : srcA[1]) + k0;
        gload_lds16(s0, &lds[b2][mat][kh][wave * 16][0]);
        gload_lds16(s1, &lds[b2][mat][kh][128 + wave * 16][0]);
    };

    // frag reads: row = R0 + (lane&15); phys octet = (lane>>4) ^ ((lane>>1)&3)
    const int physoff   = ((lane >> 4) ^ ((lane >> 1) & 3)) * 8;
    const int arow_base = wr * 128 + (lane & 15);
    const int brow_base = wc * 64  + (lane & 15);

    f32x4 acc[8][4];
    #pragma unroll
    for (int i = 0; i < 8; ++i)
        #pragma unroll
        for (int j = 0; j < 4; ++j)
            acc[i][j] = f32x4{0.f, 0.f, 0.f, 0.f};

    // prologue: tile0 kh0 (loads 1-4), tile0 kh1 (5-8), tile1 kh0 (9-12)
    stage(0, 0, 0, 0);   stage(0, 1, 0, 0);
    stage(0, 0, 1, 32);  stage(0, 1, 1, 32);
    stage(1, 0, 0, 64);  stage(1, 1, 0, 64);
    VMCNT(8);                         // tile0 kh0 (oldest 4) complete
    __builtin_amdgcn_s_barrier();     // ... and published to all waves

    bf16x8 af[4], bf[4];

#define READ_A(B, KH, Q) do { \
    _Pragma("unroll") \
    for (int mf = 0; mf < 4; ++mf) \
        af[mf] = *(const bf16x8*)&lds[B][0][KH][arow_base + (Q)*64 + mf*16][physoff]; \
} while (0)
#define READ_B(B, KH) do { \
    _Pragma("unroll") \
    for (int nf = 0; nf < 4; ++nf) \
        bf[nf] = *(const bf16x8*)&lds[B][1][KH][brow_base + nf*16][physoff]; \
} while (0)
#define MFMA_Q(Q) do { \
    __builtin_amdgcn_s_setprio(1); \
    _Pragma("unroll") \
    for (int mf = 0; mf < 4; ++mf) { \
        _Pragma("unroll") \
        for (int nf = 0; nf < 4; ++nf) \
            acc[(Q)*4 + mf][nf] = __builtin_amdgcn_mfma_f32_16x16x32_bf16( \
                af[mf], bf[nf], acc[(Q)*4 + mf][nf], 0, 0, 0); \
    } \
    __builtin_amdgcn_s_setprio(0); \
} while (0)
#define BAR_A() do { SCHED0; __builtin_amdgcn_s_barrier(); SCHED0; } while (0)
#define BAR_B() __builtin_amdgcn_s_barrier()

    for (int t = 0; t < NKT - 1; ++t) {
        const int b   = t & 1;
        const int kN1 = (t + 1) * BK + 32;   // kh1 of tile t+1
        const int kN0 = (t + 2) * BK;        // kh0 of tile t+2

        // P0: (b,kh0) q0 — safe via previous P3's vmcnt(8)+barrier
        READ_A(b, 0, 0); READ_B(b, 0);
        stage(b ^ 1, 0, 1, kN1);
        BAR_A();
        MFMA_Q(0);
        BAR_B();

        // P1: (b,kh0) q1; vmcnt(8)+barrier publishes tile-t kh1 for P2/P3
        READ_A(b, 0, 1);
        stage(b ^ 1, 1, 1, kN1);
        VMCNT(8);
        BAR_A();
        MFMA_Q(1);
        BAR_B();    // also: all (b,kh0) reads done -> P2 may overwrite it

        // P2: (b,kh1) q0
        READ_A(b, 1, 0); READ_B(b, 1);
        if (t < NKT - 2) stage(b, 0, 0, kN0);
        BAR_A();
        MFMA_Q(0);
        BAR_B();

        // P3: (b,kh1) q1; vmcnt(8)+barrier publishes tile-(t+1) kh0
        READ_A(b, 1, 1);
        if (t < NKT - 2) stage(b, 1, 0, kN0);
        VMCNT(8);
        BAR_A();
        MFMA_Q(1);
        BAR_B();
    }

    // peeled last tile (no staging). Outstanding after loop (<=8):
    // {A,B(last,kh0) from NKT-3.P2/P3 ... A,B(last,kh1) from NKT-2.P0/P1}
    {
        const int b = (NKT - 1) & 1;
        VMCNT(4);                        // kh0 pair complete
        __builtin_amdgcn_s_barrier();    // published

        READ_A(b, 0, 0); READ_B(b, 0);
        BAR_A();
        MFMA_Q(0);
        BAR_B();

        READ_A(b, 0, 1);
        VMCNT(0);                        // kh1 pair complete; barrier-A publishes
        BAR_A();
        MFMA_Q(1);
        BAR_B();

        READ_A(b, 1, 0); READ_B(b, 1);
        BAR_A();
        MFMA_Q(0);
        BAR_B();

        READ_A(b, 1, 1);
        BAR_A();
        MFMA_Q(1);
    }

#undef READ_A
#undef READ_B
#undef MFMA_Q
#undef BAR_A
#undef BAR_B

    // ---- LDS-coalesced epilogue ----
    // Reuse LDS as float[2][64][256]. Two passes (acc 0..3, 4..7). Writes:
    // scaled, chunk-swizzled (phys_chunk = chunk ^ (((row>>2)&1)<<2)).
    // Reads: 1KiB/wave-instr -> f32x4 global row stores (full 128B lines).
    __builtin_amdgcn_s_barrier();   // all waves' K-loop LDS reads consumed

    float* lf = (float*)&lds[0][0][0][0][0];
    const int qw = lane >> 4;
    const int li = lane & 15;

    float scn[4];
    #pragma unroll
    for (int nf = 0; nf < 4; ++nf) {
        const int n = nb * BN + wc * 64 + nf * 16 + li;
        scn[nf] = (n < N_DIM) ? S[n] : 0.f;
    }

    #pragma unroll
    for (int p = 0; p < 2; ++p) {
        if (p) __builtin_amdgcn_s_barrier();   // pass-0 reads before pass-1 writes
        #pragma unroll
        for (int al = 0; al < 4; ++al) {
            const int a = p * 4 + al;
            #pragma unroll
            for (int nf = 0; nf < 4; ++nf) {
                #pragma unroll
                for (int r = 0; r < 4; ++r) {
                    const int row64 = al * 16 + qw * 4 + r;
                    const int col   = wc * 64 + nf * 16 + li;
                    const int pcol  = (((col >> 2) ^ (((row64 >> 2) & 1) << 2)) << 2) | (col & 3);
                    lf[wr * (64 * 256) + row64 * 256 + pcol] = acc[a][nf][r] * scn[nf];
                }
            }
        }
        __builtin_amdgcn_s_barrier();
        #pragma unroll
        for (int i = 0; i < 16; ++i) {
            const int g     = wave * 16 + i;
            const int wrg   = g >> 6;
            const int row64 = g & 63;
            const int pch   = lane ^ (((row64 >> 2) & 1) << 2);
            f32x4 v = *(const f32x4*)&lf[wrg * (64 * 256) + row64 * 256 + pch * 4];
            const int grow = mb * BM + wrg * 128 + p * 64 + row64;
            const int gcol = nb * BN + lane * 4;
            if (gcol < N_DIM)   // N_DIM % 4 == 0 -> whole f32x4 in bounds
                *(f32x4*)&O[(size_t)grow * N_DIM + gcol] = v;
        }
    }
}

// ---------------- fallback: reg staging + in-loop convert ----------------

#define FBM 128
#define FBN 128
#define FBK 32
#define FNSTEPS (K_DIM / FBK)
#define FMB (M_DIM / FBM)
#define FNB (N_DIM / FBN)
#define FNWG (FMB * FNB)

__global__ __launch_bounds__(256, 2)
void lmhead_gemm_conv(const float* __restrict__ X,
                      const int* __restrict__ Wq,
                      const float* __restrict__ S,
                      float* __restrict__ O)
{
    __shared__ unsigned short Alds[2][FBM][FBK];
    __shared__ unsigned short Blds[2][FBN][FBK];

    const int tid  = threadIdx.x;
    const int lane = tid & 63;
    const int wave = tid >> 6;
    const int wr   = wave >> 1;
    const int wc   = wave & 1;

    const int bid = blockIdx.x;
    const int wg  = (bid & 7) * (FNWG / 8) + (bid >> 3);
    const int mb  = wg % FMB;
    const int nb  = wg / FMB;

    const int srow = tid >> 1;
    const int skh  = (tid & 1) * 16;

    const float* aptr = X  + (size_t)(mb * FBM + srow) * K_DIM + skh;
    const int*   wptr = Wq + (size_t)(nb * FBN + srow) * K_DIM + skh;

    f32x4 av[4];
    i32x4 wv[4];

    auto load_tiles = [&](int k0) {
        const f32x4* ap = (const f32x4*)(aptr + k0);
        const i32x4* wp = (const i32x4*)(wptr + k0);
        av[0] = ap[0]; av[1] = ap[1]; av[2] = ap[2]; av[3] = ap[3];
        wv[0] = wp[0]; wv[1] = wp[1]; wv[2] = wp[2]; wv[3] = wp[3];
    };

    auto stage = [&](int buf) {
        unsigned int apk[8], wpk[8];
        #pragma unroll
        for (int i = 0; i < 8; ++i) {
            apk[i] = pack2(av[(2*i) >> 2][(2*i) & 3], av[(2*i+1) >> 2][(2*i+1) & 3]);
            wpk[i] = pack2((float)wv[(2*i) >> 2][(2*i) & 3], (float)wv[(2*i+1) >> 2][(2*i+1) & 3]);
        }
        *(u32x4*)&Alds[buf][srow][skh]     = u32x4{apk[0], apk[1], apk[2], apk[3]};
        *(u32x4*)&Alds[buf][srow][skh + 8] = u32x4{apk[4], apk[5], apk[6], apk[7]};
        *(u32x4*)&Blds[buf][srow][skh]     = u32x4{wpk[0], wpk[1], wpk[2], wpk[3]};
        *(u32x4*)&Blds[buf][srow][skh + 8] = u32x4{wpk[4], wpk[5], wpk[6], wpk[7]};
    };

    f32x4 acc[4][4];
    #pragma unroll
    for (int i = 0; i < 4; ++i)
        #pragma unroll
        for (int j = 0; j < 4; ++j)
            acc[i][j] = f32x4{0.f, 0.f, 0.f, 0.f};

    load_tiles(0);
    stage(0);
    __syncthreads();

    int cur = 0;
    for (int s = 0; s < FNSTEPS; ++s) {
        if (s + 1 < FNSTEPS) load_tiles((s + 1) * FBK);

        bf16x8 af[4], bfr[4];
        const int arow = wr * 64 + (lane & 15);
        const int brow = wc * 64 + (lane & 15);
        const int kb   = (lane >> 4) * 8;
        #pragma unroll
        for (int mf = 0; mf < 4; ++mf)
            af[mf] = *(const bf16x8*)&Alds[cur][arow + mf * 16][kb];
        #pragma unroll
        for (int nf = 0; nf < 4; ++nf)
            bfr[nf] = *(const bf16x8*)&Blds[cur][brow + nf * 16][kb];

        #pragma unroll
        for (int mf = 0; mf < 4; ++mf)
            #pragma unroll
            for (int nf = 0; nf < 4; ++nf)
                acc[mf][nf] = __builtin_amdgcn_mfma_f32_16x16x32_bf16(
                    af[mf], bfr[nf], acc[mf][nf], 0, 0, 0);

        if (s + 1 < FNSTEPS) stage(cur ^ 1);
        __syncthreads();
        cur ^= 1;
    }

    #pragma unroll
    for (int nf = 0; nf < 4; ++nf) {
        const int n = nb * FBN + wc * 64 + nf * 16 + (lane & 15);
        const float sc = S[n];
        #pragma unroll
        for (int mf = 0; mf < 4; ++mf) {
            const int m0 = mb * FBM + wr * 64 + mf * 16 + ((lane >> 4) << 2);
            #pragma unroll
            for (int r = 0; r < 4; ++r)
                O[(size_t)(m0 + r) * N_DIM + n] = acc[mf][nf][r] * sc;
        }
    }
}

// ---------------- launch ----------------

extern "C" void kernel_launch(void* const* d_in, const int* in_sizes, int n_in,
                              void* d_out, int out_size, void* d_ws, size_t ws_size,
                              hipStream_t stream) {
    const float* X  = (const float*)d_in[0];
    const int*   Wq = (const int*)d_in[1];
    const float* S  = (const float*)d_in[2];
    float*       O  = (float*)d_out;

    const size_t XB_BYTES = (size_t)M_DIM * K_DIM * 2;
    const size_t WB_BYTES = (size_t)N_DIM * K_DIM * 2;

    if (ws_size >= XB_BYTES + WB_BYTES) {
        unsigned short* Xb = (unsigned short*)d_ws;
        unsigned short* Wb = (unsigned short*)((char*)d_ws + XB_BYTES);
        cvt_x_kernel<<<896, 256, 0, stream>>>(X, Xb);
        cvt_w_kernel<<<2048, 256, 0, stream>>>(Wq, Wb);
        lmhead_gemm_8ph<<<NWG, 512, 0, stream>>>(Xb, Wb, S, O);
    } else {
        lmhead_gemm_conv<<<FNWG, 256, 0, stream>>>(X, Wq, S, O);
    }
}